// Round 5
// baseline (1416.072 us; speedup 1.0000x reference)
//
#include <hip/hip_runtime.h>

#define NSET 38
#define NSNAP 9
#define PART (NSNAP*NSET*64)   // 21888 floats of partial per block
#define PPB 64

typedef unsigned int uint;

// kA<CHUNKS>: each block processes CHUNKS sequential chunks of 64 points.
// 256 threads: thread t -> point q=t&63, dim-quarter dh=t>>6 (wave-uniform).
// LDS: ztT[64 dims][65 pts] f32 (transposed: ALL accesses conflict-free)
//      + memb32[64][2] u32.  Total 17.2 KB -> occupancy LDS-unconstrained.
template<int CHUNKS>
__global__ __launch_bounds__(256) __attribute__((amdgpu_waves_per_eu(4)))
void kA(const int* __restrict__ x, const float* __restrict__ w0,
        const float* __restrict__ cw, const float* __restrict__ cb,
        const float* __restrict__ pa, float* __restrict__ partial)
{
  __shared__ float ztT[64 * 65];        // [dim][pt], stride 65
  __shared__ uint  memb32[PPB * 2];     // [pt][half]

  const int tid = threadIdx.x;
  const int q  = tid & 63;              // point slot / pool dim-lane d0
  const int g  = tid >> 6;              // wave id 0..3 (uniform): dim-quarter / set-group
  const int NEG_SETS = (g == 3) ? 8 : 10;
  (void)NEG_SETS;

  #pragma unroll 1
  for (int c = 0; c < CHUNKS; ++c) {
    const int p = (blockIdx.x * CHUNKS + c) * PPB + q;

    // membership: waves 0,1 load 19 sets each (coalesced 256B rows)
    if (c) __syncthreads();             // prior chunk's memb readers done
    if (g < 2) {
      uint m = 0;
      #pragma unroll
      for (int j = 0; j < 19; ++j)
        m |= (uint)(x[(g * 19 + j) * 65536 + p] == 1) << j;
      memb32[q * 2 + g] = m;
    }
    __syncthreads();

    // conv0: pre-act for dims [16g, 16g+16) of point q (weights via s_load)
    float acc[16];
    {
      float px = -1.f + (2.f / 255.f) * (float)(p & 255);
      float py = -1.f + (2.f / 255.f) * (float)(p >> 8);
      #pragma unroll
      for (int d = 0; d < 16; ++d) {
        int dd = (g << 4) + d;
        acc[d] = fmaf(px, w0[2 * dd], fmaf(py, w0[2 * dd + 1], cb[dd]));
      }
    }

    #pragma unroll 1
    for (int s = 0; s < NSNAP; ++s) {
      // prelu -> ztT (pool in PReLU domain; conv-domain recovered in kB)
      __syncthreads();                  // prev snapshot's ztT readers done
      #pragma unroll
      for (int d = 0; d < 16; ++d) {
        int dd = (g << 4) + d;
        float zv = acc[d];
        float a = pa[(s << 6) + dd];    // uniform -> s_load
        ztT[dd * 65 + q] = zv > 0.f ? zv : a * zv;
      }
      __syncthreads();                  // ztT ready

      // pool: thread (d0=q, g) pools its 10 sets over 64 points.
      // mask bits come from the SCALAR pipe (readfirstlane + window shift).
      float run[10];
      #pragma unroll
      for (int j = 0; j < 10; ++j) run[j] = -3e38f;
      const float NEG = -1e38f;
      #pragma unroll 2
      for (int pp = 0; pp < PPB; ++pp) {
        float v = ztT[q * 65 + pp];     // lane d0=q reads row q, col pp
        uint mlo = __builtin_amdgcn_readfirstlane(memb32[pp * 2 + 0]);
        uint mhi = __builtin_amdgcn_readfirstlane(memb32[pp * 2 + 1]);
        // window: bits j -> set g*10+j
        uint win = (g == 0) ? mlo
                 : (g == 1) ? ((mlo >> 10) | (mhi << 9))
                 : (g == 2) ? (mhi >> 1)
                            : (mhi >> 11);
        #pragma unroll
        for (int j = 0; j < 10; ++j)
          run[j] = fmaxf(run[j], ((win >> j) & 1u) ? v : NEG);
      }
      {
        float* pb = partial + (size_t)blockIdx.x * PART + s * (NSET * 64) + q;
        #pragma unroll
        for (int j = 0; j < 10; ++j) {
          int set = g * 10 + j;
          if (set < NSET) {
            if (CHUNKS == 1 || c == 0) pb[set * 64] = run[j];
            else                       pb[set * 64] = fmaxf(pb[set * 64], run[j]);
          }
        }
      }

      // next layer: rz from ztT (conflict-free b32 column), weights via
      // d-outer contiguous-64-k scalar loads (R3's proven pattern).
      if (s < 8) {
        float rz[64];
        #pragma unroll
        for (int k = 0; k < 64; ++k) rz[k] = ztT[k * 65 + q];
        const float* W = cw + (s << 12) + (g << 10);   // rows [16g,16g+16)
        #pragma unroll 4
        for (int d = 0; d < 16; ++d) {
          float a = cb[((s + 1) << 6) + (g << 4) + d];
          #pragma unroll
          for (int k = 0; k < 64; ++k)
            a = fmaf(rz[k], W[(d << 6) + k], a);
          acc[d] = a;
        }
      }
    }
  }
}

// zero-point snapshots: conv-domain and prelu-domain, 9 x 64 each
__global__ void kZ(const float* __restrict__ cw, const float* __restrict__ cb,
                   const float* __restrict__ pa,
                   float* __restrict__ zsc, float* __restrict__ zsp)
{
  __shared__ float zl[64];
  int d = threadIdx.x;  // 64 threads
  float z = cb[d];
  #pragma unroll 1
  for (int s = 0; s < NSNAP; ++s) {
    zsc[(s << 6) + d] = z;
    float a = pa[(s << 6) + d];
    float zp = z > 0.f ? z : a * z;
    zsp[(s << 6) + d] = zp;
    if (s < 8) {
      __syncthreads();
      zl[d] = zp;
      __syncthreads();
      float acc = cb[((s + 1) << 6) + d];
      for (int k = 0; k < 64; ++k)
        acc = fmaf(zl[k], cw[(s << 12) + (d << 6) + k], acc);
      z = acc;
    }
  }
}

// reduce block partials -> pooled -> feat (conv & prelu snapshots)
__global__ void kB(const float* __restrict__ partial, int nblk,
                   const float* __restrict__ zsc, const float* __restrict__ zsp,
                   const float* __restrict__ pa, float* __restrict__ feat)
{
  int idx = blockIdx.x * 256 + threadIdx.x;
  if (idx >= NSNAP * NSET * 64) return;
  int s = idx / (NSET * 64);
  int r = idx - s * (NSET * 64);
  int set = r >> 6;
  int d = r & 63;
  float mx = -3e38f;
  const float* p0 = partial + idx;   // layout [blk][s][set][d] matches idx
  #pragma unroll 4
  for (int blk = 0; blk < nblk; ++blk)
    mx = fmaxf(mx, p0[(size_t)blk * PART]);
  int b = set / 19, cc = set - b * 19;
  float even_v, odd_v;
  if (mx < -5e37f) {                 // empty set -> zero-point snapshot
    even_v = zsc[(s << 6) + d];
    odd_v  = zsp[(s << 6) + d];
  } else {
    odd_v = mx;                      // prelu-domain max
    float a = pa[(s << 6) + d];
    even_v = mx > 0.f ? mx : mx / a; // inverse prelu
  }
  size_t fb = ((size_t)b * 18 + 2 * s) * 1216 + cc * 64 + d;
  feat[fb] = even_v;
  feat[fb + 1216] = odd_v;
}

// out[b][17-lr][srow] = scale*<feat[b][lr], fcw[lr][srow]> + fcb[lr][srow]
__global__ __launch_bounds__(256) void kC(const float* __restrict__ feat,
    const float* __restrict__ fcw, const float* __restrict__ fcb,
    float* __restrict__ out)
{
  __shared__ float f0[1216], f1[1216];
  int lr = blockIdx.y;
  int chunk = blockIdx.x;       // 0..31, 16 rows each
  int tid = threadIdx.x;
  for (int i = tid; i < 1216; i += 256) {
    f0[i] = feat[(size_t)(0 * 18 + lr) * 1216 + i];
    f1[i] = feat[(size_t)(1 * 18 + lr) * 1216 + i];
  }
  __syncthreads();
  int wv = tid >> 6, lane = tid & 63;
  float scale = 1.f / sqrtf(1216.f);
  int l = 17 - lr;
  #pragma unroll 1
  for (int rr = 0; rr < 4; ++rr) {
    int srow = (chunk << 4) + (wv << 2) + rr;
    const float* wrow = fcw + ((size_t)lr * 512 + srow) * 1216;
    float pp0 = 0.f, pp1 = 0.f;
    #pragma unroll
    for (int k = 0; k < 19; ++k) {
      float w = wrow[(k << 6) + lane];
      pp0 = fmaf(w, f0[(k << 6) + lane], pp0);
      pp1 = fmaf(w, f1[(k << 6) + lane], pp1);
    }
    #pragma unroll
    for (int off = 32; off; off >>= 1) {
      pp0 += __shfl_xor(pp0, off, 64);
      pp1 += __shfl_xor(pp1, off, 64);
    }
    if (lane == 0) {
      float b = fcb[lr * 512 + srow];
      out[((size_t)0 * 18 + l) * 512 + srow] = fmaf(scale, pp0, b);
      out[((size_t)1 * 18 + l) * 512 + srow] = fmaf(scale, pp1, b);
    }
  }
}

extern "C" void kernel_launch(void* const* d_in, const int* in_sizes, int n_in,
                              void* d_out, int out_size, void* d_ws, size_t ws_size,
                              hipStream_t stream) {
  const int*   x   = (const int*)d_in[0];
  const float* w0  = (const float*)d_in[1];
  const float* cw  = (const float*)d_in[2];
  const float* cb  = (const float*)d_in[3];
  const float* pa  = (const float*)d_in[4];
  const float* fcw = (const float*)d_in[5];
  const float* fcb = (const float*)d_in[6];
  float* ws = (float*)d_ws;
  float* out = (float*)d_out;

  const size_t tail = (size_t)NSNAP * 64 * 2 + (size_t)2 * 18 * 1216;
  #define NEED(n) (((size_t)(n) * PART + tail) * 4)

  int nblk;
  if      (ws_size >= NEED(1024)) nblk = 1024;
  else if (ws_size >= NEED(512))  nblk = 512;
  else                            nblk = 256;

  float* partial = ws;
  float* zsc  = ws + (size_t)nblk * PART;
  float* zsp  = zsc + NSNAP * 64;
  float* feat = zsp + NSNAP * 64;

  hipLaunchKernelGGL(kZ, dim3(1), dim3(64), 0, stream, cw, cb, pa, zsc, zsp);

  if (nblk == 1024) {
    hipLaunchKernelGGL(kA<1>, dim3(1024), dim3(256), 0, stream,
                       x, w0, cw, cb, pa, partial);
  } else if (nblk == 512) {
    hipLaunchKernelGGL(kA<2>, dim3(512), dim3(256), 0, stream,
                       x, w0, cw, cb, pa, partial);
  } else {
    hipLaunchKernelGGL(kA<4>, dim3(256), dim3(256), 0, stream,
                       x, w0, cw, cb, pa, partial);
  }

  hipLaunchKernelGGL(kB, dim3(86), dim3(256), 0, stream,
                     partial, nblk, zsc, zsp, pa, feat);
  hipLaunchKernelGGL(kC, dim3(32, 18), dim3(256), 0, stream, feat, fcw, fcb, out);
}

// Round 7
// 796.714 us; speedup vs baseline: 1.7774x; 1.7774x over previous
//
#include <hip/hip_runtime.h>

#define NSET 38
#define NSNAP 9
#define PART (NSNAP*NSET*64)   // 21888 floats of partial per block
#define PPB 64

typedef unsigned long long ull;
typedef unsigned int uint;

// kA<CHUNKS>: 256 threads, PPB=64 points per chunk.
// Roles: lane q = point (prelu/MLP) or dim d0 (pool); wave g = dim-quarter
// (MLP) or set-group (pool, 10/10/10/8 split).
// LDS: zt[64 pts][65] f32 + memb[64] u64 = 17152 B -> 4 blocks/CU.
// waves_per_eu(4,4): pin min=max so the allocator targets exactly 4 waves/EU
// (VGPR cap 128; live ~95). R5's failure was unbounded (4) -> 64 VGPR + spill.
template<int CHUNKS>
__global__ __launch_bounds__(256) __attribute__((amdgpu_waves_per_eu(4, 4)))
void kA(const int* __restrict__ x, const float* __restrict__ w0,
        const float* __restrict__ cw, const float* __restrict__ cb,
        const float* __restrict__ pa, float* __restrict__ partial)
{
  __shared__ float zt[PPB * 65];     // [pt][dim], stride 65 (odd: conflict-free)
  __shared__ ull memb[PPB];

  const int tid = threadIdx.x;
  const int q = tid & 63;
  const int g = __builtin_amdgcn_readfirstlane(tid >> 6);  // wave id, uniform
  const int sbase = g * 10;                  // set groups 10/10/10/8
  const int nset = (g == 3) ? 8 : 10;
  const int negi = __float_as_int(-1e38f);   // uniform

  #pragma unroll 1
  for (int c = 0; c < CHUNKS; ++c) {
    const int p = (blockIdx.x * CHUNKS + c) * PPB + q;

    if (c) __syncthreads();          // prior chunk's memb/zt readers done
    if (tid < 128) {                 // waves 0,1: 19 sets each, coalesced
      const int half = tid >> 6;
      uint m = 0;
      #pragma unroll
      for (int j = 0; j < 19; ++j)
        m |= (uint)(x[(half * 19 + j) * 65536 + p] == 1) << j;
      ((uint*)&memb[q])[half] = m;
    }
    __syncthreads();
    // compact halves {bits 0..18, bits 32..50} -> contiguous bits 0..37,
    // so that set s == bit s (the R6 bug: pool assumed this, build didn't).
    if (tid < 64) {
      ull v = memb[tid];
      memb[tid] = (v & 0x7FFFFull) | ((v >> 32) << 19);
    }
    __syncthreads();

    // conv0: pre-act dims [16g,16g+16) of point q; weights via s_load
    float acc[16];
    {
      float px = -1.f + (2.f / 255.f) * (float)(p & 255);
      float py = -1.f + (2.f / 255.f) * (float)(p >> 8);
      #pragma unroll
      for (int d = 0; d < 16; ++d) {
        int dd = (g << 4) + d;
        acc[d] = fmaf(px, w0[2 * dd], fmaf(py, w0[2 * dd + 1], cb[dd]));
      }
    }

    #pragma unroll 1
    for (int s = 0; s < NSNAP; ++s) {
      // prelu -> zt (pool in PReLU domain; conv-domain recovered in kB2)
      __syncthreads();               // prev snapshot's zt readers done
      #pragma unroll
      for (int d = 0; d < 16; ++d) {
        int dd = (g << 4) + d;
        float zv = acc[d];
        float a = pa[(s << 6) + dd]; // uniform -> s_load
        zt[q * 65 + dd] = zv > 0.f ? zv : a * zv;
      }
      __syncthreads();               // zt ready

      // pool: thread (d0=q, g) pools its 10 (or 8) sets over 64 points.
      // select = sext(bit) + bfi against -1e38: pure VALU, no LDS table.
      float run[10];
      #pragma unroll
      for (int j = 0; j < 10; ++j) run[j] = -3e38f;
      #pragma unroll 2
      for (int pp = 0; pp < PPB; pp += 2) {
        float v0 = zt[pp * 65 + q];          // lanes q consecutive: clean
        float v1 = zt[(pp + 1) * 65 + q];
        uint w0v = (uint)(memb[pp]     >> sbase);   // set s at bit s now
        uint w1v = (uint)(memb[pp + 1] >> sbase);
        #pragma unroll
        for (int j = 0; j < 10; ++j) {
          int m0 = (int)(w0v << (31 - j)) >> 31;    // sext of bit j
          int m1 = (int)(w1v << (31 - j)) >> 31;
          float t0 = __int_as_float((__float_as_int(v0) & m0) | (negi & ~m0));
          float t1 = __int_as_float((__float_as_int(v1) & m1) | (negi & ~m1));
          run[j] = fmaxf(fmaxf(run[j], t0), t1);    // max3-fusable
        }
      }
      {
        float* pb = partial + (size_t)blockIdx.x * PART + s * (NSET * 64) + q;
        #pragma unroll
        for (int j = 0; j < 10; ++j) {
          if (j < nset) {            // uniform guard (wave 3: 8 sets)
            int set = sbase + j;
            if (CHUNKS == 1 || c == 0) pb[set * 64] = run[j];
            else                       pb[set * 64] = fmaxf(pb[set * 64], run[j]);
          }
        }
      }

      // next layer: rz from zt (conflict-free b32), weights via d-outer
      // contiguous-64-k scalar loads (R3's proven codegen).
      if (s < 8) {
        float rz[64];
        #pragma unroll
        for (int k = 0; k < 64; ++k) rz[k] = zt[q * 65 + k];
        const float* W = cw + (s << 12) + (g << 10);   // rows [16g,16g+16)
        #pragma unroll 4
        for (int d = 0; d < 16; ++d) {
          float a = cb[((s + 1) << 6) + (g << 4) + d];
          #pragma unroll
          for (int k = 0; k < 64; ++k)
            a = fmaf(rz[k], W[(d << 6) + k], a);
          acc[d] = a;
        }
      }
    }
  }
}

// stage-1 reduce: y-slice reduces nblk/32 block-partials, in-place into the
// slice's first block (each (y,idx) owns its slot; read-before-write per thread)
__global__ __launch_bounds__(256) void kB1(float* __restrict__ partial, int per)
{
  int idx = blockIdx.x * 256 + threadIdx.x;
  if (idx >= PART) return;
  float* p0 = partial + (size_t)blockIdx.y * per * PART + idx;
  float mx = -3e38f;
  #pragma unroll 8
  for (int b = 0; b < per; ++b)
    mx = fmaxf(mx, p0[(size_t)b * PART]);
  p0[0] = mx;
}

// stage-2: reduce 32 slices + zero-point chain (folded kZ) + build feat
__global__ __launch_bounds__(256) void kB2(const float* __restrict__ partial,
    int per, const float* __restrict__ cw, const float* __restrict__ cb,
    const float* __restrict__ pa, float* __restrict__ feat)
{
  __shared__ float zl[64];
  __shared__ float zc[NSNAP][64];
  __shared__ float zp[NSNAP][64];
  int tid = threadIdx.x;
  int d = tid & 63;
  float z = cb[d];
  #pragma unroll 1
  for (int s = 0; s < NSNAP; ++s) {
    if (tid < 64) {
      zc[s][d] = z;
      float a = pa[(s << 6) + d];
      float v = z > 0.f ? z : a * z;
      zp[s][d] = v;
      zl[d] = v;
    }
    __syncthreads();
    if (s < 8) {
      if (tid < 64) {
        float a2 = cb[((s + 1) << 6) + d];
        for (int k = 0; k < 64; ++k)
          a2 = fmaf(zl[k], cw[(s << 12) + (d << 6) + k], a2);
        z = a2;
      }
    }
    __syncthreads();
  }

  int idx = blockIdx.x * 256 + tid;
  if (idx >= PART) return;
  int s = idx / (NSET * 64);
  int r = idx - s * (NSET * 64);
  int set = r >> 6;
  int dd = r & 63;
  float mx = -3e38f;
  #pragma unroll
  for (int y = 0; y < 32; ++y)
    mx = fmaxf(mx, partial[(size_t)y * per * PART + idx]);
  int b = set / 19, cc = set - b * 19;
  float even_v, odd_v;
  if (mx < -5e37f) {                 // empty set -> zero-point snapshot
    even_v = zc[s][dd];
    odd_v  = zp[s][dd];
  } else {
    odd_v = mx;                      // prelu-domain max
    float a = pa[(s << 6) + dd];
    even_v = mx > 0.f ? mx : mx / a; // inverse prelu
  }
  size_t fb = ((size_t)b * 18 + 2 * s) * 1216 + cc * 64 + dd;
  feat[fb] = even_v;
  feat[fb + 1216] = odd_v;
}

// out[b][17-lr][srow] = scale*<feat[b][lr], fcw[lr][srow]> + fcb[lr][srow]
__global__ __launch_bounds__(256) void kC(const float* __restrict__ feat,
    const float* __restrict__ fcw, const float* __restrict__ fcb,
    float* __restrict__ out)
{
  __shared__ float f0[1216], f1[1216];
  int lr = blockIdx.y;
  int chunk = blockIdx.x;       // 0..31, 16 rows each
  int tid = threadIdx.x;
  for (int i = tid; i < 1216; i += 256) {
    f0[i] = feat[(size_t)(0 * 18 + lr) * 1216 + i];
    f1[i] = feat[(size_t)(1 * 18 + lr) * 1216 + i];
  }
  __syncthreads();
  int wv = tid >> 6, lane = tid & 63;
  float scale = 1.f / sqrtf(1216.f);
  int l = 17 - lr;
  #pragma unroll 1
  for (int rr = 0; rr < 4; ++rr) {
    int srow = (chunk << 4) + (wv << 2) + rr;
    const float* wrow = fcw + ((size_t)lr * 512 + srow) * 1216;
    float pp0 = 0.f, pp1 = 0.f;
    #pragma unroll
    for (int k = 0; k < 19; ++k) {
      float w = wrow[(k << 6) + lane];
      pp0 = fmaf(w, f0[(k << 6) + lane], pp0);
      pp1 = fmaf(w, f1[(k << 6) + lane], pp1);
    }
    #pragma unroll
    for (int off = 32; off; off >>= 1) {
      pp0 += __shfl_xor(pp0, off, 64);
      pp1 += __shfl_xor(pp1, off, 64);
    }
    if (lane == 0) {
      float b = fcb[lr * 512 + srow];
      out[((size_t)0 * 18 + l) * 512 + srow] = fmaf(scale, pp0, b);
      out[((size_t)1 * 18 + l) * 512 + srow] = fmaf(scale, pp1, b);
    }
  }
}

extern "C" void kernel_launch(void* const* d_in, const int* in_sizes, int n_in,
                              void* d_out, int out_size, void* d_ws, size_t ws_size,
                              hipStream_t stream) {
  const int*   x   = (const int*)d_in[0];
  const float* w0  = (const float*)d_in[1];
  const float* cw  = (const float*)d_in[2];
  const float* cb  = (const float*)d_in[3];
  const float* pa  = (const float*)d_in[4];
  const float* fcw = (const float*)d_in[5];
  const float* fcb = (const float*)d_in[6];
  float* ws = (float*)d_ws;
  float* out = (float*)d_out;

  const size_t tail = (size_t)2 * 18 * 1216;          // feat
  #define NEED(n) (((size_t)(n) * PART + tail) * 4)

  int nblk;
  if      (ws_size >= NEED(1024)) nblk = 1024;
  else if (ws_size >= NEED(512))  nblk = 512;
  else                            nblk = 256;

  float* partial = ws;
  float* feat = ws + (size_t)nblk * PART;
  const int per = nblk >> 5;    // blocks per kB1 y-slice (32 slices)

  if (nblk == 1024) {
    hipLaunchKernelGGL(kA<1>, dim3(1024), dim3(256), 0, stream,
                       x, w0, cw, cb, pa, partial);
  } else if (nblk == 512) {
    hipLaunchKernelGGL(kA<2>, dim3(512), dim3(256), 0, stream,
                       x, w0, cw, cb, pa, partial);
  } else {
    hipLaunchKernelGGL(kA<4>, dim3(256), dim3(256), 0, stream,
                       x, w0, cw, cb, pa, partial);
  }

  hipLaunchKernelGGL(kB1, dim3(86, 32), dim3(256), 0, stream, partial, per);
  hipLaunchKernelGGL(kB2, dim3(86), dim3(256), 0, stream,
                     partial, per, cw, cb, pa, feat);
  hipLaunchKernelGGL(kC, dim3(32, 18), dim3(256), 0, stream, feat, fcw, fcb, out);
}

// Round 8
// 305.142 us; speedup vs baseline: 4.6407x; 2.6110x over previous
//
#include <hip/hip_runtime.h>

#define NSET 38
#define NSNAP 9
#define PART (NSNAP*NSET*64)   // 21888 floats of partial per block
#define PPB 128
#define ZSTR 65                // odd stride: every zt access <=2-way (free)

typedef unsigned long long ull;
typedef unsigned int uint;

// kA<CHUNKS>: 256 threads, PPB=128 points per chunk.
// Roles: q=tid&127 point (prelu/MLP, dim-half h=tid>>7); pool: d0=tid&63,
// g=tid>>6 set-group (10/10/10/8).
// LDS: zt[128][65] f32 + memb[128] u64 = 34304 B -> 4 blocks/CU -> the
// allocator's occupancy target is LDS-bound at 4 waves/EU (VGPR cap 128),
// so it has no incentive to shrink below the ~90 live VGPRs (R3 mechanism;
// R5/R7 spilled because 17 KB LDS let it target 8 waves/EU = 64 VGPR).
template<int CHUNKS>
__global__ __launch_bounds__(256)
void kA(const int* __restrict__ x, const float* __restrict__ w0,
        const float* __restrict__ cw, const float* __restrict__ cb,
        const float* __restrict__ pa, float* __restrict__ partial)
{
  __shared__ float zt[PPB * ZSTR];   // [pt][dim]
  __shared__ ull memb[PPB];

  const int tid = threadIdx.x;
  const int q  = tid & 127;
  const int h  = __builtin_amdgcn_readfirstlane(tid >> 7);  // dim-half, uniform
  const int d0 = tid & 63;
  const int g  = __builtin_amdgcn_readfirstlane(tid >> 6);  // set-group, uniform
  const int sbase = g * 10;                  // 10/10/10/8
  const int nset = (g == 3) ? 8 : 10;
  const int negi = __float_as_int(-1e38f);

  #pragma unroll 1
  for (int c = 0; c < CHUNKS; ++c) {
    const int p = (blockIdx.x * CHUNKS + c) * PPB + q;

    // membership: half=tid>>7 loads 19 set-rows for point q (512B coalesced)
    if (c) __syncthreads();          // prior chunk's memb/zt readers done
    {
      uint m = 0;
      #pragma unroll
      for (int j = 0; j < 19; ++j)
        m |= (uint)(x[((tid >> 7) * 19 + j) * 65536 + p] == 1) << j;
      ((uint*)&memb[q])[tid >> 7] = m;
    }
    __syncthreads();
    // compact {bits 0..18, bits 32..50} -> contiguous 0..37 (set s == bit s)
    if (tid < PPB) {
      ull v = memb[tid];
      memb[tid] = (v & 0x7FFFFull) | ((v >> 32) << 19);
    }

    // conv0: pre-act dims [32h,32h+32) of point q; weights via s_load
    float acc[32];
    {
      float px = -1.f + (2.f / 255.f) * (float)(p & 255);
      float py = -1.f + (2.f / 255.f) * (float)(p >> 8);
      #pragma unroll
      for (int d = 0; d < 32; ++d) {
        int dd = (h << 5) + d;
        acc[d] = fmaf(px, w0[2 * dd], fmaf(py, w0[2 * dd + 1], cb[dd]));
      }
    }
    __syncthreads();                 // memb compaction done

    #pragma unroll 1
    for (int s = 0; s < NSNAP; ++s) {
      // prelu -> zt (pool in PReLU domain; conv-domain recovered in kB2)
      if (s) __syncthreads();        // prev snapshot's zt readers done
      #pragma unroll
      for (int d = 0; d < 32; ++d) {
        int dd = (h << 5) + d;
        float zv = acc[d];
        float a = pa[(s << 6) + dd]; // uniform -> s_load
        zt[q * ZSTR + dd] = zv > 0.f ? zv : a * zv;
      }
      __syncthreads();               // zt ready

      // pool: thread (d0,g) pools its 10 (or 8) sets over 128 points.
      // select = bfe_i32(sign-ext bit) + bfi vs -1e38 + max3: pure VALU.
      float run[10];
      #pragma unroll
      for (int j = 0; j < 10; ++j) run[j] = -3e38f;
      #pragma unroll 2
      for (int pp = 0; pp < PPB; pp += 2) {
        float v0 = zt[pp * ZSTR + d0];
        float v1 = zt[(pp + 1) * ZSTR + d0];
        uint w0v = (uint)(memb[pp]     >> sbase);  // uniform b64 broadcast
        uint w1v = (uint)(memb[pp + 1] >> sbase);
        #pragma unroll
        for (int j = 0; j < 10; ++j) {
          int m0 = (int)(w0v << (31 - j)) >> 31;
          int m1 = (int)(w1v << (31 - j)) >> 31;
          float t0 = __int_as_float((__float_as_int(v0) & m0) | (negi & ~m0));
          float t1 = __int_as_float((__float_as_int(v1) & m1) | (negi & ~m1));
          run[j] = fmaxf(fmaxf(run[j], t0), t1);   // max3-fusable
        }
      }
      {
        float* pb = partial + (size_t)blockIdx.x * PART + s * (NSET * 64) + d0;
        #pragma unroll
        for (int j = 0; j < 10; ++j) {
          if (j < nset) {            // uniform guard (wave 3: 8 sets)
            int set = sbase + j;
            if (CHUNKS == 1 || c == 0) pb[set * 64] = run[j];
            else                       pb[set * 64] = fmaxf(pb[set * 64], run[j]);
          }
        }
      }

      // next layer: rz from zt (b32, odd stride -> free), weights via
      // d-outer contiguous-64-k scalar loads (R3's proven codegen).
      if (s < 8) {
        float rz[64];
        #pragma unroll
        for (int k = 0; k < 64; ++k) rz[k] = zt[q * ZSTR + k];
        const float* W = cw + (s << 12) + (h << 11);   // rows [32h,32h+32)
        #pragma unroll 4
        for (int d = 0; d < 32; ++d) {
          float a = cb[((s + 1) << 6) + (h << 5) + d];
          #pragma unroll
          for (int k = 0; k < 64; ++k)
            a = fmaf(rz[k], W[(d << 6) + k], a);
          acc[d] = a;
        }
      }
    }
  }
}

// stage-1 reduce: y-slice reduces nblk/32 block-partials, in-place into the
// slice's first block (each (y,idx) owns its slot; read-before-write per thread)
__global__ __launch_bounds__(256) void kB1(float* __restrict__ partial, int per)
{
  int idx = blockIdx.x * 256 + threadIdx.x;
  if (idx >= PART) return;
  float* p0 = partial + (size_t)blockIdx.y * per * PART + idx;
  float mx = -3e38f;
  #pragma unroll 8
  for (int b = 0; b < per; ++b)
    mx = fmaxf(mx, p0[(size_t)b * PART]);
  p0[0] = mx;
}

// stage-2: reduce 32 slices + zero-point chain (folded kZ) + build feat
__global__ __launch_bounds__(256) void kB2(const float* __restrict__ partial,
    int per, const float* __restrict__ cw, const float* __restrict__ cb,
    const float* __restrict__ pa, float* __restrict__ feat)
{
  __shared__ float zl[64];
  __shared__ float zc[NSNAP][64];
  __shared__ float zp[NSNAP][64];
  int tid = threadIdx.x;
  int d = tid & 63;
  float z = cb[d];
  #pragma unroll 1
  for (int s = 0; s < NSNAP; ++s) {
    if (tid < 64) {
      zc[s][d] = z;
      float a = pa[(s << 6) + d];
      float v = z > 0.f ? z : a * z;
      zp[s][d] = v;
      zl[d] = v;
    }
    __syncthreads();
    if (s < 8) {
      if (tid < 64) {
        float a2 = cb[((s + 1) << 6) + d];
        for (int k = 0; k < 64; ++k)
          a2 = fmaf(zl[k], cw[(s << 12) + (d << 6) + k], a2);
        z = a2;
      }
    }
    __syncthreads();
  }

  int idx = blockIdx.x * 256 + tid;
  if (idx >= PART) return;
  int s = idx / (NSET * 64);
  int r = idx - s * (NSET * 64);
  int set = r >> 6;
  int dd = r & 63;
  float mx = -3e38f;
  #pragma unroll
  for (int y = 0; y < 32; ++y)
    mx = fmaxf(mx, partial[(size_t)y * per * PART + idx]);
  int b = set / 19, cc = set - b * 19;
  float even_v, odd_v;
  if (mx < -5e37f) {                 // empty set -> zero-point snapshot
    even_v = zc[s][dd];
    odd_v  = zp[s][dd];
  } else {
    odd_v = mx;                      // prelu-domain max
    float a = pa[(s << 6) + dd];
    even_v = mx > 0.f ? mx : mx / a; // inverse prelu
  }
  size_t fb = ((size_t)b * 18 + 2 * s) * 1216 + cc * 64 + dd;
  feat[fb] = even_v;
  feat[fb + 1216] = odd_v;
}

// out[b][17-lr][srow] = scale*<feat[b][lr], fcw[lr][srow]> + fcb[lr][srow]
__global__ __launch_bounds__(256) void kC(const float* __restrict__ feat,
    const float* __restrict__ fcw, const float* __restrict__ fcb,
    float* __restrict__ out)
{
  __shared__ float f0[1216], f1[1216];
  int lr = blockIdx.y;
  int chunk = blockIdx.x;       // 0..31, 16 rows each
  int tid = threadIdx.x;
  for (int i = tid; i < 1216; i += 256) {
    f0[i] = feat[(size_t)(0 * 18 + lr) * 1216 + i];
    f1[i] = feat[(size_t)(1 * 18 + lr) * 1216 + i];
  }
  __syncthreads();
  int wv = tid >> 6, lane = tid & 63;
  float scale = 1.f / sqrtf(1216.f);
  int l = 17 - lr;
  #pragma unroll 1
  for (int rr = 0; rr < 4; ++rr) {
    int srow = (chunk << 4) + (wv << 2) + rr;
    const float* wrow = fcw + ((size_t)lr * 512 + srow) * 1216;
    float pp0 = 0.f, pp1 = 0.f;
    #pragma unroll
    for (int k = 0; k < 19; ++k) {
      float w = wrow[(k << 6) + lane];
      pp0 = fmaf(w, f0[(k << 6) + lane], pp0);
      pp1 = fmaf(w, f1[(k << 6) + lane], pp1);
    }
    #pragma unroll
    for (int off = 32; off; off >>= 1) {
      pp0 += __shfl_xor(pp0, off, 64);
      pp1 += __shfl_xor(pp1, off, 64);
    }
    if (lane == 0) {
      float b = fcb[lr * 512 + srow];
      out[((size_t)0 * 18 + l) * 512 + srow] = fmaf(scale, pp0, b);
      out[((size_t)1 * 18 + l) * 512 + srow] = fmaf(scale, pp1, b);
    }
  }
}

extern "C" void kernel_launch(void* const* d_in, const int* in_sizes, int n_in,
                              void* d_out, int out_size, void* d_ws, size_t ws_size,
                              hipStream_t stream) {
  const int*   x   = (const int*)d_in[0];
  const float* w0  = (const float*)d_in[1];
  const float* cw  = (const float*)d_in[2];
  const float* cb  = (const float*)d_in[3];
  const float* pa  = (const float*)d_in[4];
  const float* fcw = (const float*)d_in[5];
  const float* fcb = (const float*)d_in[6];
  float* ws = (float*)d_ws;
  float* out = (float*)d_out;

  const size_t tail = (size_t)2 * 18 * 1216;          // feat
  #define NEED(n) (((size_t)(n) * PART + tail) * 4)

  int nblk;
  if      (ws_size >= NEED(512)) nblk = 512;
  else                           nblk = 256;

  float* partial = ws;
  float* feat = ws + (size_t)nblk * PART;
  const int per = nblk >> 5;    // blocks per kB1 y-slice (32 slices)

  if (nblk == 512) {
    hipLaunchKernelGGL(kA<1>, dim3(512), dim3(256), 0, stream,
                       x, w0, cw, cb, pa, partial);
  } else {
    hipLaunchKernelGGL(kA<2>, dim3(256), dim3(256), 0, stream,
                       x, w0, cw, cb, pa, partial);
  }

  hipLaunchKernelGGL(kB1, dim3(86, 32), dim3(256), 0, stream, partial, per);
  hipLaunchKernelGGL(kB2, dim3(86), dim3(256), 0, stream,
                     partial, per, cw, cb, pa, feat);
  hipLaunchKernelGGL(kC, dim3(32, 18), dim3(256), 0, stream, feat, fcw, fcb, out);
}

// Round 9
// 272.223 us; speedup vs baseline: 5.2019x; 1.1209x over previous
//
#include <hip/hip_runtime.h>

#define NSET 38
#define NSNAP 9
#define PART (NSNAP*NSET*64)   // 21888 floats of partial per block
#define PPB 64
#define ZSTR 65                // odd stride: every zt b32 access <=2-way (free)

typedef unsigned long long ull;
typedef unsigned int uint;

// kA<CHUNKS>: 256 threads, PPB=64 points per chunk, grid 1024 blocks -> 4
// blocks/CU resident (R8 failed to reach 4 only because its 512-block grid
// couldn't supply them). LDS padded to ~37.6 KB: the allocator's occupancy
// target is LDS-bound at 4 waves/EU -> VGPR cap 128 (R3/R8-proven governor;
// R5/R7 spilled because 17 KB LDS let it target 8 waves/EU = 64-VGPR cap).
// Roles: MLP/prelu: thread t -> point q=t&63, dim-quarter g=t>>6 (acc[16]).
// Pool: lane d0=t&63 = dim, wave g = set-group (10/10/10/8), masks via
// __ballot (lane=point) -> SGPR pair -> s_bitcmp/s_cselect + v_cndmask.
template<int CHUNKS>
__global__ __launch_bounds__(256)
void kA(const int* __restrict__ x, const float* __restrict__ w0,
        const float* __restrict__ cw, const float* __restrict__ cb,
        const float* __restrict__ pa, float* __restrict__ partial)
{
  __shared__ float zt[PPB * ZSTR];   // [pt][dim] 16640 B
  __shared__ ull memb[PPB];          // 512 B
  __shared__ float padlds[5120];     // 20480 B occupancy governor (see above)

  const int tid = threadIdx.x;
  const int q  = tid & 63;           // point (MLP) / dim d0 (pool)
  const int g  = __builtin_amdgcn_readfirstlane(tid >> 6);  // wave id, uniform
  const int sbase = g * 10;          // set groups 10/10/10/8
  const int nset = (g == 3) ? 8 : 10;
  const float NEG = -1e38f;

  if ((int)blockIdx.x < 0) padlds[tid] = 0.f;   // keep pad alive, never runs

  #pragma unroll 1
  for (int c = 0; c < CHUNKS; ++c) {
    const int p = (blockIdx.x * CHUNKS + c) * PPB + q;

    // membership: waves 0,1 load 19 set-rows each (256B coalesced rows)
    if (c) __syncthreads();          // prior chunk's memb/zt readers done
    if (tid < 128) {
      const int half = tid >> 6;
      uint m = 0;
      #pragma unroll
      for (int j = 0; j < 19; ++j)
        m |= (uint)(x[(half * 19 + j) * 65536 + p] == 1) << j;
      ((uint*)&memb[q])[half] = m;
    }
    __syncthreads();
    // compact {bits 0..18, 32..50} -> contiguous 0..37 (set s == bit s)
    if (tid < 64) {
      ull v = memb[tid];
      memb[tid] = (v & 0x7FFFFull) | ((v >> 32) << 19);
    }
    __syncthreads();

    // per-set lane-masks over this chunk's 64 points (lane = point):
    // blt[j] bit pp = point pp in set (sbase+j). Uniform u64 -> SGPR pair.
    ull blt[10];
    {
      uint win = (uint)(memb[q] >> sbase) & ((g == 3) ? 0xFFu : 0x3FFu);
      #pragma unroll
      for (int j = 0; j < 10; ++j)
        blt[j] = __ballot((win >> j) & 1u);
    }

    // conv0: pre-act dims [16g,16g+16) of point q; weights via s_load
    float acc[16];
    {
      float px = -1.f + (2.f / 255.f) * (float)(p & 255);
      float py = -1.f + (2.f / 255.f) * (float)(p >> 8);
      #pragma unroll
      for (int d = 0; d < 16; ++d) {
        int dd = (g << 4) + d;
        acc[d] = fmaf(px, w0[2 * dd], fmaf(py, w0[2 * dd + 1], cb[dd]));
      }
    }

    #pragma unroll 1
    for (int s = 0; s < NSNAP; ++s) {
      // prelu -> zt (pool in PReLU domain; conv-domain recovered in kB2)
      if (s) __syncthreads();        // prev snapshot's zt readers done
      #pragma unroll
      for (int d = 0; d < 16; ++d) {
        int dd = (g << 4) + d;
        float zv = acc[d];
        float a = pa[(s << 6) + dd]; // uniform -> s_load
        zt[q * ZSTR + dd] = zv > 0.f ? zv : a * zv;
      }
      __syncthreads();               // zt ready

      // pool: wave g pools its 10 (or 8) sets over 64 points; lane = dim.
      // select: wave-uniform bit -> s_cselect mask + v_cndmask; max3 fuse.
      float run[10];
      #pragma unroll
      for (int j = 0; j < 10; ++j) run[j] = -3e38f;
      #pragma unroll 1
      for (int pp = 0; pp < PPB; pp += 4) {
        float v0 = zt[(pp + 0) * ZSTR + q];
        float v1 = zt[(pp + 1) * ZSTR + q];
        float v2 = zt[(pp + 2) * ZSTR + q];
        float v3 = zt[(pp + 3) * ZSTR + q];
        #pragma unroll
        for (int j = 0; j < 10; ++j) {
          float t0 = ((blt[j] >> (pp + 0)) & 1ull) ? v0 : NEG;
          float t1 = ((blt[j] >> (pp + 1)) & 1ull) ? v1 : NEG;
          float t2 = ((blt[j] >> (pp + 2)) & 1ull) ? v2 : NEG;
          float t3 = ((blt[j] >> (pp + 3)) & 1ull) ? v3 : NEG;
          run[j] = fmaxf(fmaxf(run[j], fmaxf(t0, t1)), fmaxf(t2, t3));
        }
      }
      {
        float* pb = partial + (size_t)blockIdx.x * PART + s * (NSET * 64) + q;
        #pragma unroll
        for (int j = 0; j < 10; ++j) {
          if (j < nset) {            // uniform guard (wave 3: 8 sets)
            int set = sbase + j;
            if (CHUNKS == 1 || c == 0) pb[set * 64] = run[j];
            else                       pb[set * 64] = fmaxf(pb[set * 64], run[j]);
          }
        }
      }

      // next layer: rz from zt (b32, 2-way max), weights via d-outer
      // contiguous-64-k scalar loads (R3's proven codegen).
      if (s < 8) {
        float rz[64];
        #pragma unroll
        for (int k = 0; k < 64; ++k) rz[k] = zt[q * ZSTR + k];
        const float* W = cw + (s << 12) + (g << 10);   // rows [16g,16g+16)
        #pragma unroll 4
        for (int d = 0; d < 16; ++d) {
          float a = cb[((s + 1) << 6) + (g << 4) + d];
          #pragma unroll
          for (int k = 0; k < 64; ++k)
            a = fmaf(rz[k], W[(d << 6) + k], a);
          acc[d] = a;
        }
      }
    }
  }
}

// stage-1 reduce: y-slice reduces nblk/32 block-partials, in-place into the
// slice's first block (each (y,idx) owns its slot; read-before-write per thread)
__global__ __launch_bounds__(256) void kB1(float* __restrict__ partial, int per)
{
  int idx = blockIdx.x * 256 + threadIdx.x;
  if (idx >= PART) return;
  float* p0 = partial + (size_t)blockIdx.y * per * PART + idx;
  float mx = -3e38f;
  #pragma unroll 8
  for (int b = 0; b < per; ++b)
    mx = fmaxf(mx, p0[(size_t)b * PART]);
  p0[0] = mx;
}

// stage-2: reduce 32 slices + zero-point chain (folded kZ) + build feat
__global__ __launch_bounds__(256) void kB2(const float* __restrict__ partial,
    int per, const float* __restrict__ cw, const float* __restrict__ cb,
    const float* __restrict__ pa, float* __restrict__ feat)
{
  __shared__ float zl[64];
  __shared__ float zc[NSNAP][64];
  __shared__ float zp[NSNAP][64];
  int tid = threadIdx.x;
  int d = tid & 63;
  float z = cb[d];
  #pragma unroll 1
  for (int s = 0; s < NSNAP; ++s) {
    if (tid < 64) {
      zc[s][d] = z;
      float a = pa[(s << 6) + d];
      float v = z > 0.f ? z : a * z;
      zp[s][d] = v;
      zl[d] = v;
    }
    __syncthreads();
    if (s < 8) {
      if (tid < 64) {
        float a2 = cb[((s + 1) << 6) + d];
        for (int k = 0; k < 64; ++k)
          a2 = fmaf(zl[k], cw[(s << 12) + (d << 6) + k], a2);
        z = a2;
      }
    }
    __syncthreads();
  }

  int idx = blockIdx.x * 256 + tid;
  if (idx >= PART) return;
  int s = idx / (NSET * 64);
  int r = idx - s * (NSET * 64);
  int set = r >> 6;
  int dd = r & 63;
  float mx = -3e38f;
  #pragma unroll
  for (int y = 0; y < 32; ++y)
    mx = fmaxf(mx, partial[(size_t)y * per * PART + idx]);
  int b = set / 19, cc = set - b * 19;
  float even_v, odd_v;
  if (mx < -5e37f) {                 // empty set -> zero-point snapshot
    even_v = zc[s][dd];
    odd_v  = zp[s][dd];
  } else {
    odd_v = mx;                      // prelu-domain max
    float a = pa[(s << 6) + dd];
    even_v = mx > 0.f ? mx : mx / a; // inverse prelu
  }
  size_t fb = ((size_t)b * 18 + 2 * s) * 1216 + cc * 64 + dd;
  feat[fb] = even_v;
  feat[fb + 1216] = odd_v;
}

// out[b][17-lr][srow] = scale*<feat[b][lr], fcw[lr][srow]> + fcb[lr][srow]
__global__ __launch_bounds__(256) void kC(const float* __restrict__ feat,
    const float* __restrict__ fcw, const float* __restrict__ fcb,
    float* __restrict__ out)
{
  __shared__ float f0[1216], f1[1216];
  int lr = blockIdx.y;
  int chunk = blockIdx.x;       // 0..31, 16 rows each
  int tid = threadIdx.x;
  for (int i = tid; i < 1216; i += 256) {
    f0[i] = feat[(size_t)(0 * 18 + lr) * 1216 + i];
    f1[i] = feat[(size_t)(1 * 18 + lr) * 1216 + i];
  }
  __syncthreads();
  int wv = tid >> 6, lane = tid & 63;
  float scale = 1.f / sqrtf(1216.f);
  int l = 17 - lr;
  #pragma unroll 1
  for (int rr = 0; rr < 4; ++rr) {
    int srow = (chunk << 4) + (wv << 2) + rr;
    const float* wrow = fcw + ((size_t)lr * 512 + srow) * 1216;
    float pp0 = 0.f, pp1 = 0.f;
    #pragma unroll
    for (int k = 0; k < 19; ++k) {
      float w = wrow[(k << 6) + lane];
      pp0 = fmaf(w, f0[(k << 6) + lane], pp0);
      pp1 = fmaf(w, f1[(k << 6) + lane], pp1);
    }
    #pragma unroll
    for (int off = 32; off; off >>= 1) {
      pp0 += __shfl_xor(pp0, off, 64);
      pp1 += __shfl_xor(pp1, off, 64);
    }
    if (lane == 0) {
      float b = fcb[lr * 512 + srow];
      out[((size_t)0 * 18 + l) * 512 + srow] = fmaf(scale, pp0, b);
      out[((size_t)1 * 18 + l) * 512 + srow] = fmaf(scale, pp1, b);
    }
  }
}

extern "C" void kernel_launch(void* const* d_in, const int* in_sizes, int n_in,
                              void* d_out, int out_size, void* d_ws, size_t ws_size,
                              hipStream_t stream) {
  const int*   x   = (const int*)d_in[0];
  const float* w0  = (const float*)d_in[1];
  const float* cw  = (const float*)d_in[2];
  const float* cb  = (const float*)d_in[3];
  const float* pa  = (const float*)d_in[4];
  const float* fcw = (const float*)d_in[5];
  const float* fcb = (const float*)d_in[6];
  float* ws = (float*)d_ws;
  float* out = (float*)d_out;

  const size_t tail = (size_t)2 * 18 * 1216;          // feat
  #define NEED(n) (((size_t)(n) * PART + tail) * 4)

  int nblk;
  if      (ws_size >= NEED(1024)) nblk = 1024;
  else if (ws_size >= NEED(512))  nblk = 512;
  else                            nblk = 256;

  float* partial = ws;
  float* feat = ws + (size_t)nblk * PART;
  const int per = nblk >> 5;    // blocks per kB1 y-slice (32 slices)

  if (nblk == 1024) {
    hipLaunchKernelGGL(kA<1>, dim3(1024), dim3(256), 0, stream,
                       x, w0, cw, cb, pa, partial);
  } else if (nblk == 512) {
    hipLaunchKernelGGL(kA<2>, dim3(512), dim3(256), 0, stream,
                       x, w0, cw, cb, pa, partial);
  } else {
    hipLaunchKernelGGL(kA<4>, dim3(256), dim3(256), 0, stream,
                       x, w0, cw, cb, pa, partial);
  }

  hipLaunchKernelGGL(kB1, dim3(86, 32), dim3(256), 0, stream, partial, per);
  hipLaunchKernelGGL(kB2, dim3(86), dim3(256), 0, stream,
                     partial, per, cw, cb, pa, feat);
  hipLaunchKernelGGL(kC, dim3(32, 18), dim3(256), 0, stream, feat, fcw, fcb, out);
}

// Round 10
// 203.007 us; speedup vs baseline: 6.9755x; 1.3410x over previous
//
#include <hip/hip_runtime.h>

#define NSET 38
#define NSNAP 9
#define PART (NSNAP*NSET*64)   // 21888 floats of partial per block
#define PPB 64
#define ZSTR 65                // odd stride: every zt b32 access <=2-way (free)
#define ASTR 40                // addend row: 4 set-groups of 10 (8B-aligned)

typedef unsigned long long ull;
typedef unsigned int uint;

// kA<CHUNKS>: 256 threads, PPB=64 points/chunk, grid 1024 -> 4 blocks/CU.
// MLP/prelu: thread t -> point q=t&63, dim-quarter g=t>>6 (acc[16]).
// Pool: lane = dim, wave g = set-group (10/10/10/8); mask select via LDS
// addend table (0 / -1e38) read as uniform b64 broadcasts -> v_add + v_max3,
// ZERO per-element SALU (R9's bottleneck: s_lshr/s_cselect per (pt,set) on
// the single per-CU scalar unit ~ 115us serial).
// LDS 27.4 KB -> occupancy LDS-capped at 5 blocks/CU -> VGPR cap ~102 >> ~60
// live (LDS is the proven allocator governor; R5/R7 spilled at 17 KB).
template<int CHUNKS>
__global__ __launch_bounds__(256)
void kA(const int* __restrict__ x, const float* __restrict__ w0,
        const float* __restrict__ cw, const float* __restrict__ cb,
        const float* __restrict__ pa, float* __restrict__ partial)
{
  __shared__ float zt[PPB * ZSTR];     // 16640 B [pt][dim]
  __shared__ float addend[PPB * ASTR]; // 10240 B [pt][set-slot]
  __shared__ uint  memb2[PPB * 2];     //   512 B [pt][half]

  const int tid = threadIdx.x;
  const int q  = tid & 63;             // point (MLP) / dim (pool)
  const int g  = __builtin_amdgcn_readfirstlane(tid >> 6);  // wave id, uniform
  const int sbase = g * 10;            // set groups 10/10/10/8
  const int nset = (g == 3) ? 8 : 10;

  #pragma unroll 1
  for (int c = 0; c < CHUNKS; ++c) {
    const int p = (blockIdx.x * CHUNKS + c) * PPB + q;

    // membership halves: waves 0,1 load 19 set-rows each (coalesced)
    if (c) __syncthreads();            // prior chunk's LDS readers done
    if (tid < 128) {
      const int half = tid >> 6;
      uint m = 0;
      #pragma unroll
      for (int j = 0; j < 19; ++j)
        m |= (uint)(x[(half * 19 + j) * 65536 + p] == 1) << j;
      memb2[q * 2 + half] = m;
    }
    __syncthreads();

    // addend[pt][j] = in-set ? 0 : -1e38 ; built once, reused all 9 snaps.
    // thread -> pt=tid>>2, 10 slots at (tid&3)*10.
    {
      const int pt = tid >> 2;
      const int jb = (tid & 3) * 10;
      uint lo = memb2[pt * 2], hi = memb2[pt * 2 + 1];
      #pragma unroll
      for (int jj = 0; jj < 10; ++jj) {
        int j = jb + jj;
        uint bit = (j < 19) ? ((lo >> j) & 1u)
                 : (j < 38) ? ((hi >> (j - 19)) & 1u) : 0u;
        addend[pt * ASTR + j] = bit ? 0.f : -1e38f;
      }
    }

    // conv0: pre-act dims [16g,16g+16) of point q; weights via s_load
    float acc[16];
    {
      float px = -1.f + (2.f / 255.f) * (float)(p & 255);
      float py = -1.f + (2.f / 255.f) * (float)(p >> 8);
      #pragma unroll
      for (int d = 0; d < 16; ++d) {
        int dd = (g << 4) + d;
        acc[d] = fmaf(px, w0[2 * dd], fmaf(py, w0[2 * dd + 1], cb[dd]));
      }
    }
    __syncthreads();                   // addend ready

    #pragma unroll 1
    for (int s = 0; s < NSNAP; ++s) {
      // prelu -> zt (pool in PReLU domain; conv-domain recovered in kB2)
      if (s) __syncthreads();          // prev snapshot's zt readers done
      #pragma unroll
      for (int d = 0; d < 16; ++d) {
        int dd = (g << 4) + d;
        float zv = acc[d];
        float a = pa[(s << 6) + dd];   // uniform -> s_load
        zt[q * ZSTR + dd] = zv > 0.f ? zv : a * zv;
      }
      __syncthreads();                 // zt ready

      // pool: wave g pools its 10 (or 8) sets over 64 points; lane = dim.
      // per 2-pt body: 2 b32 + 10 uniform b64 + 20 v_add + 10 v_max3.
      float run[10];
      #pragma unroll
      for (int j = 0; j < 10; ++j) run[j] = -3e38f;
      #pragma unroll 2
      for (int pp = 0; pp < PPB; pp += 2) {
        float v0 = zt[(pp + 0) * ZSTR + q];
        float v1 = zt[(pp + 1) * ZSTR + q];
        const float2* A0 = (const float2*)&addend[(pp + 0) * ASTR + sbase];
        const float2* A1 = (const float2*)&addend[(pp + 1) * ASTR + sbase];
        float2 a0[5], a1[5];
        #pragma unroll
        for (int t = 0; t < 5; ++t) { a0[t] = A0[t]; a1[t] = A1[t]; }
        #pragma unroll
        for (int t = 0; t < 5; ++t) {
          run[2*t]   = fmaxf(fmaxf(run[2*t],   v0 + a0[t].x), v1 + a1[t].x);
          run[2*t+1] = fmaxf(fmaxf(run[2*t+1], v0 + a0[t].y), v1 + a1[t].y);
        }
      }
      {
        float* pb = partial + (size_t)blockIdx.x * PART + s * (NSET * 64) + q;
        #pragma unroll
        for (int j = 0; j < 10; ++j) {
          if (j < nset) {              // uniform guard (wave 3: 8 sets)
            int set = sbase + j;
            if (CHUNKS == 1 || c == 0) pb[set * 64] = run[j];
            else                       pb[set * 64] = fmaxf(pb[set * 64], run[j]);
          }
        }
      }

      // next layer: k-chunked rz[16] (live ~60 VGPR -> register-resident at
      // any cap >=64); weights d-outer contiguous via s_load (R3 codegen).
      if (s < 8) {
        const float* W = cw + (s << 12) + (g << 10);   // rows [16g,16g+16)
        #pragma unroll
        for (int d = 0; d < 16; ++d)
          acc[d] = cb[((s + 1) << 6) + (g << 4) + d];
        #pragma unroll
        for (int kc = 0; kc < 4; ++kc) {
          float rz[16];
          #pragma unroll
          for (int k = 0; k < 16; ++k)
            rz[k] = zt[q * ZSTR + (kc << 4) + k];
          #pragma unroll
          for (int d = 0; d < 16; ++d) {
            const float* wr = &W[(d << 6) + (kc << 4)];
            float a = acc[d];
            #pragma unroll
            for (int k = 0; k < 16; ++k)
              a = fmaf(rz[k], wr[k], a);
            acc[d] = a;
          }
        }
      }
    }
  }
}

// stage-1 reduce: y-slice reduces nblk/32 block-partials, in-place into the
// slice's first block (each (y,idx) owns its slot; read-before-write per thread)
__global__ __launch_bounds__(256) void kB1(float* __restrict__ partial, int per)
{
  int idx = blockIdx.x * 256 + threadIdx.x;
  if (idx >= PART) return;
  float* p0 = partial + (size_t)blockIdx.y * per * PART + idx;
  float mx = -3e38f;
  #pragma unroll 8
  for (int b = 0; b < per; ++b)
    mx = fmaxf(mx, p0[(size_t)b * PART]);
  p0[0] = mx;
}

// stage-2: reduce 32 slices + zero-point chain (folded kZ) + build feat
__global__ __launch_bounds__(256) void kB2(const float* __restrict__ partial,
    int per, const float* __restrict__ cw, const float* __restrict__ cb,
    const float* __restrict__ pa, float* __restrict__ feat)
{
  __shared__ float zl[64];
  __shared__ float zc[NSNAP][64];
  __shared__ float zp[NSNAP][64];
  int tid = threadIdx.x;
  int d = tid & 63;
  float z = cb[d];
  #pragma unroll 1
  for (int s = 0; s < NSNAP; ++s) {
    if (tid < 64) {
      zc[s][d] = z;
      float a = pa[(s << 6) + d];
      float v = z > 0.f ? z : a * z;
      zp[s][d] = v;
      zl[d] = v;
    }
    __syncthreads();
    if (s < 8) {
      if (tid < 64) {
        float a2 = cb[((s + 1) << 6) + d];
        for (int k = 0; k < 64; ++k)
          a2 = fmaf(zl[k], cw[(s << 12) + (d << 6) + k], a2);
        z = a2;
      }
    }
    __syncthreads();
  }

  int idx = blockIdx.x * 256 + tid;
  if (idx >= PART) return;
  int s = idx / (NSET * 64);
  int r = idx - s * (NSET * 64);
  int set = r >> 6;
  int dd = r & 63;
  float mx = -3e38f;
  #pragma unroll
  for (int y = 0; y < 32; ++y)
    mx = fmaxf(mx, partial[(size_t)y * per * PART + idx]);
  int b = set / 19, cc = set - b * 19;
  float even_v, odd_v;
  if (mx < -5e37f) {                 // empty set -> zero-point snapshot
    even_v = zc[s][dd];
    odd_v  = zp[s][dd];
  } else {
    odd_v = mx;                      // prelu-domain max
    float a = pa[(s << 6) + dd];
    even_v = mx > 0.f ? mx : mx / a; // inverse prelu
  }
  size_t fb = ((size_t)b * 18 + 2 * s) * 1216 + cc * 64 + dd;
  feat[fb] = even_v;
  feat[fb + 1216] = odd_v;
}

// out[b][17-lr][srow] = scale*<feat[b][lr], fcw[lr][srow]> + fcb[lr][srow]
__global__ __launch_bounds__(256) void kC(const float* __restrict__ feat,
    const float* __restrict__ fcw, const float* __restrict__ fcb,
    float* __restrict__ out)
{
  __shared__ float f0[1216], f1[1216];
  int lr = blockIdx.y;
  int chunk = blockIdx.x;       // 0..31, 16 rows each
  int tid = threadIdx.x;
  for (int i = tid; i < 1216; i += 256) {
    f0[i] = feat[(size_t)(0 * 18 + lr) * 1216 + i];
    f1[i] = feat[(size_t)(1 * 18 + lr) * 1216 + i];
  }
  __syncthreads();
  int wv = tid >> 6, lane = tid & 63;
  float scale = 1.f / sqrtf(1216.f);
  int l = 17 - lr;
  #pragma unroll 1
  for (int rr = 0; rr < 4; ++rr) {
    int srow = (chunk << 4) + (wv << 2) + rr;
    const float* wrow = fcw + ((size_t)lr * 512 + srow) * 1216;
    float pp0 = 0.f, pp1 = 0.f;
    #pragma unroll
    for (int k = 0; k < 19; ++k) {
      float w = wrow[(k << 6) + lane];
      pp0 = fmaf(w, f0[(k << 6) + lane], pp0);
      pp1 = fmaf(w, f1[(k << 6) + lane], pp1);
    }
    #pragma unroll
    for (int off = 32; off; off >>= 1) {
      pp0 += __shfl_xor(pp0, off, 64);
      pp1 += __shfl_xor(pp1, off, 64);
    }
    if (lane == 0) {
      float b = fcb[lr * 512 + srow];
      out[((size_t)0 * 18 + l) * 512 + srow] = fmaf(scale, pp0, b);
      out[((size_t)1 * 18 + l) * 512 + srow] = fmaf(scale, pp1, b);
    }
  }
}

extern "C" void kernel_launch(void* const* d_in, const int* in_sizes, int n_in,
                              void* d_out, int out_size, void* d_ws, size_t ws_size,
                              hipStream_t stream) {
  const int*   x   = (const int*)d_in[0];
  const float* w0  = (const float*)d_in[1];
  const float* cw  = (const float*)d_in[2];
  const float* cb  = (const float*)d_in[3];
  const float* pa  = (const float*)d_in[4];
  const float* fcw = (const float*)d_in[5];
  const float* fcb = (const float*)d_in[6];
  float* ws = (float*)d_ws;
  float* out = (float*)d_out;

  const size_t tail = (size_t)2 * 18 * 1216;          // feat
  #define NEED(n) (((size_t)(n) * PART + tail) * 4)

  int nblk;
  if      (ws_size >= NEED(1024)) nblk = 1024;
  else if (ws_size >= NEED(512))  nblk = 512;
  else                            nblk = 256;

  float* partial = ws;
  float* feat = ws + (size_t)nblk * PART;
  const int per = nblk >> 5;    // blocks per kB1 y-slice (32 slices)

  if (nblk == 1024) {
    hipLaunchKernelGGL(kA<1>, dim3(1024), dim3(256), 0, stream,
                       x, w0, cw, cb, pa, partial);
  } else if (nblk == 512) {
    hipLaunchKernelGGL(kA<2>, dim3(512), dim3(256), 0, stream,
                       x, w0, cw, cb, pa, partial);
  } else {
    hipLaunchKernelGGL(kA<4>, dim3(256), dim3(256), 0, stream,
                       x, w0, cw, cb, pa, partial);
  }

  hipLaunchKernelGGL(kB1, dim3(86, 32), dim3(256), 0, stream, partial, per);
  hipLaunchKernelGGL(kB2, dim3(86), dim3(256), 0, stream,
                     partial, per, cw, cb, pa, feat);
  hipLaunchKernelGGL(kC, dim3(32, 18), dim3(256), 0, stream, feat, fcw, fcb, out);
}

// Round 11
// 162.812 us; speedup vs baseline: 8.6976x; 1.2469x over previous
//
#include <hip/hip_runtime.h>

#define NSET 38
#define NSNAP 9
#define PART (NSNAP*NSET*64)   // 21888 floats of partial per block
#define PPB 64
#define ZSTR 65                // odd stride: all zt b32 access <=2-way (free)
#define ASTR 40                // addend row: 4 set-groups of 10 (8B-aligned)
#define WHALF (8*64*64)        // fp16 weight elements

typedef unsigned int uint;
typedef __fp16 half8 __attribute__((ext_vector_type(8)));
typedef float  f32x4 __attribute__((ext_vector_type(4)));

// kA<CHUNKS>: 256 threads, PPB=64 points/chunk, grid 1024 -> 4 blocks/CU.
// conv0/prelu-s0: thread t -> point q=t&63, dim-quarter g (acc[16]).
// Pool: lane=dim, wave g = set-group (10/10/10/8), LDS addend table (R10).
// Layers 1..8: per-wave MFMA 16x16x32 f16 — wave g owns pts [16g,16g+16),
// all 64 dims: 2 A-frags (k-tiles) x 4 d-tiles x 2 K-step mfma = 8 MFMA
// replaces 1024 scalar FMA + the s_load latency wall (R10: ~5 weight rows
// in flight under 102-SGPR budget covered ~160 of ~300cyc -> 43% idle).
// fp16 weights/activations at matmul inputs only (zt & accum stay f32):
// rel err ~2^-11/layer x 8 layers ~1e-3 << 1.24e-2 threshold.
// LDS 27.6 KB -> allocator occupancy target 5 blocks/CU -> VGPR cap ~102
// >> ~70 live (LDS-as-governor, proven R3/R8/R10).
template<int CHUNKS>
__global__ __launch_bounds__(256)
void kA(const int* __restrict__ x, const float* __restrict__ w0,
        const float* __restrict__ cw, const float* __restrict__ cb,
        const float* __restrict__ pa, const __fp16* __restrict__ wf,
        float* __restrict__ partial)
{
  __shared__ float zt[PPB * ZSTR];     // 16640 B [pt][dim]
  __shared__ float addend[PPB * ASTR]; // 10240 B [pt][set-slot]
  __shared__ uint  memb2[PPB * 2];     //   512 B [pt][half]

  const int tid = threadIdx.x;
  const int q  = tid & 63;             // point (conv0) / dim (pool)
  const int g  = __builtin_amdgcn_readfirstlane(tid >> 6);  // wave id, uniform
  const int l  = tid & 63;             // lane
  const int lr = l & 15;               // mfma: A-row offset / B,C col (dim)
  const int lg = l >> 4;               // mfma: k-group / C row-group
  const int sbase = g * 10;            // set groups 10/10/10/8
  const int nset = (g == 3) ? 8 : 10;

  #pragma unroll 1
  for (int c = 0; c < CHUNKS; ++c) {
    const int p = (blockIdx.x * CHUNKS + c) * PPB + q;

    // membership halves: waves 0,1 load 19 set-rows each (coalesced)
    if (c) __syncthreads();            // prior chunk's LDS readers done
    if (tid < 128) {
      const int half = tid >> 6;
      uint m = 0;
      #pragma unroll
      for (int j = 0; j < 19; ++j)
        m |= (uint)(x[(half * 19 + j) * 65536 + p] == 1) << j;
      memb2[q * 2 + half] = m;
    }
    __syncthreads();

    // addend[pt][j] = in-set ? 0 : -1e38 (built once, reused all 9 snaps)
    {
      const int pt = tid >> 2;
      const int jb = (tid & 3) * 10;
      uint lo = memb2[pt * 2], hi = memb2[pt * 2 + 1];
      #pragma unroll
      for (int jj = 0; jj < 10; ++jj) {
        int j = jb + jj;
        uint bit = (j < 19) ? ((lo >> j) & 1u)
                 : (j < 38) ? ((hi >> (j - 19)) & 1u) : 0u;
        addend[pt * ASTR + j] = bit ? 0.f : -1e38f;
      }
    }

    // conv0: pre-act dims [16g,16g+16) of point q; weights via s_load
    float acc0[16];
    {
      float px = -1.f + (2.f / 255.f) * (float)(p & 255);
      float py = -1.f + (2.f / 255.f) * (float)(p >> 8);
      #pragma unroll
      for (int d = 0; d < 16; ++d) {
        int dd = (g << 4) + d;
        acc0[d] = fmaf(px, w0[2 * dd], fmaf(py, w0[2 * dd + 1], cb[dd]));
      }
    }
    __syncthreads();                   // addend ready

    f32x4 Cf[4];                       // layer-(s) pre-act frags (s>=1)

    #pragma unroll 1
    for (int s = 0; s < NSNAP; ++s) {
      // prelu -> zt (pool in PReLU domain; conv-domain recovered in kB2)
      if (s) __syncthreads();          // prev snapshot's zt readers done
      if (s == 0) {
        #pragma unroll
        for (int d = 0; d < 16; ++d) {
          int dd = (g << 4) + d;
          float zv = acc0[d];
          float a = pa[dd];            // uniform -> s_load
          zt[q * ZSTR + dd] = zv > 0.f ? zv : a * zv;
        }
      } else {
        // frag mapping: pt = 16g + 4*lg + r, dim = 16*dt + lr
        #pragma unroll
        for (int dt = 0; dt < 4; ++dt) {
          float a = pa[(s << 6) + (dt << 4) + lr];
          #pragma unroll
          for (int r = 0; r < 4; ++r) {
            float zv = Cf[dt][r];
            zt[((g << 4) + (lg << 2) + r) * ZSTR + (dt << 4) + lr] =
                zv > 0.f ? zv : a * zv;
          }
        }
      }
      __syncthreads();                 // zt ready

      // pool: wave g pools its 10 (or 8) sets over 64 points; lane = dim.
      // per 2-pt body: 2 b32 + 10 uniform b64 + 20 v_add + 10 v_max3 (R10).
      float run[10];
      #pragma unroll
      for (int j = 0; j < 10; ++j) run[j] = -3e38f;
      #pragma unroll 2
      for (int pp = 0; pp < PPB; pp += 2) {
        float v0 = zt[(pp + 0) * ZSTR + q];
        float v1 = zt[(pp + 1) * ZSTR + q];
        const float2* A0 = (const float2*)&addend[(pp + 0) * ASTR + sbase];
        const float2* A1 = (const float2*)&addend[(pp + 1) * ASTR + sbase];
        float2 a0[5], a1[5];
        #pragma unroll
        for (int t = 0; t < 5; ++t) { a0[t] = A0[t]; a1[t] = A1[t]; }
        #pragma unroll
        for (int t = 0; t < 5; ++t) {
          run[2*t]   = fmaxf(fmaxf(run[2*t],   v0 + a0[t].x), v1 + a1[t].x);
          run[2*t+1] = fmaxf(fmaxf(run[2*t+1], v0 + a0[t].y), v1 + a1[t].y);
        }
      }
      {
        float* pb = partial + (size_t)blockIdx.x * PART + s * (NSET * 64) + q;
        #pragma unroll
        for (int j = 0; j < 10; ++j) {
          if (j < nset) {              // uniform guard (wave 3: 8 sets)
            int set = sbase + j;
            if (CHUNKS == 1 || c == 0) pb[set * 64] = run[j];
            else                       pb[set * 64] = fmaxf(pb[set * 64], run[j]);
          }
        }
      }

      // next layer via MFMA: wave g computes pts [16g,16g+16) x 64 dims.
      if (s < 8) {
        // A-frags (2 k-tiles): lane holds row (16g+lr), k = kt*32+lg*8+j
        const float* zr = &zt[((g << 4) + lr) * ZSTR + (lg << 3)];
        half8 a0, a1;
        #pragma unroll
        for (int j = 0; j < 8; ++j) a0[j] = (__fp16)zr[j];
        #pragma unroll
        for (int j = 0; j < 8; ++j) a1[j] = (__fp16)zr[32 + j];
        // B-frags from preconverted fp16 W[s][d][k]: lane = row d=16dt+lr,
        // 8 consecutive k at kt*32+lg*8 -> one b128 per (dt,kt).
        const __fp16* wb = wf + ((size_t)s << 12);
        #pragma unroll
        for (int dt = 0; dt < 4; ++dt) {
          float bias = cb[((s + 1) << 6) + (dt << 4) + lr];
          f32x4 a4 = {bias, bias, bias, bias};
          half8 b0 = *(const half8*)&wb[(((dt << 4) + lr) << 6) + (lg << 3)];
          half8 b1 = *(const half8*)&wb[(((dt << 4) + lr) << 6) + 32 + (lg << 3)];
          a4 = __builtin_amdgcn_mfma_f32_16x16x32_f16(a0, b0, a4, 0, 0, 0);
          a4 = __builtin_amdgcn_mfma_f32_16x16x32_f16(a1, b1, a4, 0, 0, 0);
          Cf[dt] = a4;
        }
      }
    }
  }
}

// one-shot: cw f32 -> fp16 (RNE) into workspace
__global__ __launch_bounds__(256) void kW(const float* __restrict__ cw,
                                          __fp16* __restrict__ wf)
{
  int i = blockIdx.x * 256 + threadIdx.x;
  if (i < WHALF) wf[i] = (__fp16)cw[i];
}

// stage-1 reduce: y-slice reduces nblk/32 block-partials, in-place into the
// slice's first block (each (y,idx) owns its slot; read-before-write per thread)
__global__ __launch_bounds__(256) void kB1(float* __restrict__ partial, int per)
{
  int idx = blockIdx.x * 256 + threadIdx.x;
  if (idx >= PART) return;
  float* p0 = partial + (size_t)blockIdx.y * per * PART + idx;
  float mx = -3e38f;
  #pragma unroll 8
  for (int b = 0; b < per; ++b)
    mx = fmaxf(mx, p0[(size_t)b * PART]);
  p0[0] = mx;
}

// stage-2: reduce 32 slices + zero-point chain (folded kZ, f32 exact) + feat
__global__ __launch_bounds__(256) void kB2(const float* __restrict__ partial,
    int per, const float* __restrict__ cw, const float* __restrict__ cb,
    const float* __restrict__ pa, float* __restrict__ feat)
{
  __shared__ float zl[64];
  __shared__ float zc[NSNAP][64];
  __shared__ float zp[NSNAP][64];
  int tid = threadIdx.x;
  int d = tid & 63;
  float z = cb[d];
  #pragma unroll 1
  for (int s = 0; s < NSNAP; ++s) {
    if (tid < 64) {
      zc[s][d] = z;
      float a = pa[(s << 6) + d];
      float v = z > 0.f ? z : a * z;
      zp[s][d] = v;
      zl[d] = v;
    }
    __syncthreads();
    if (s < 8) {
      if (tid < 64) {
        float a2 = cb[((s + 1) << 6) + d];
        for (int k = 0; k < 64; ++k)
          a2 = fmaf(zl[k], cw[(s << 12) + (d << 6) + k], a2);
        z = a2;
      }
    }
    __syncthreads();
  }

  int idx = blockIdx.x * 256 + tid;
  if (idx >= PART) return;
  int s = idx / (NSET * 64);
  int r = idx - s * (NSET * 64);
  int set = r >> 6;
  int dd = r & 63;
  float mx = -3e38f;
  #pragma unroll
  for (int y = 0; y < 32; ++y)
    mx = fmaxf(mx, partial[(size_t)y * per * PART + idx]);
  int b = set / 19, cc = set - b * 19;
  float even_v, odd_v;
  if (mx < -5e37f) {                 // empty set -> zero-point snapshot
    even_v = zc[s][dd];
    odd_v  = zp[s][dd];
  } else {
    odd_v = mx;                      // prelu-domain max
    float a = pa[(s << 6) + dd];
    even_v = mx > 0.f ? mx : mx / a; // inverse prelu
  }
  size_t fb = ((size_t)b * 18 + 2 * s) * 1216 + cc * 64 + dd;
  feat[fb] = even_v;
  feat[fb + 1216] = odd_v;
}

// out[b][17-lr][srow] = scale*<feat[b][lr], fcw[lr][srow]> + fcb[lr][srow]
__global__ __launch_bounds__(256) void kC(const float* __restrict__ feat,
    const float* __restrict__ fcw, const float* __restrict__ fcb,
    float* __restrict__ out)
{
  __shared__ float f0[1216], f1[1216];
  int lr = blockIdx.y;
  int chunk = blockIdx.x;       // 0..31, 16 rows each
  int tid = threadIdx.x;
  for (int i = tid; i < 1216; i += 256) {
    f0[i] = feat[(size_t)(0 * 18 + lr) * 1216 + i];
    f1[i] = feat[(size_t)(1 * 18 + lr) * 1216 + i];
  }
  __syncthreads();
  int wv = tid >> 6, lane = tid & 63;
  float scale = 1.f / sqrtf(1216.f);
  int l = 17 - lr;
  #pragma unroll 1
  for (int rr = 0; rr < 4; ++rr) {
    int srow = (chunk << 4) + (wv << 2) + rr;
    const float* wrow = fcw + ((size_t)lr * 512 + srow) * 1216;
    float pp0 = 0.f, pp1 = 0.f;
    #pragma unroll
    for (int k = 0; k < 19; ++k) {
      float w = wrow[(k << 6) + lane];
      pp0 = fmaf(w, f0[(k << 6) + lane], pp0);
      pp1 = fmaf(w, f1[(k << 6) + lane], pp1);
    }
    #pragma unroll
    for (int off = 32; off; off >>= 1) {
      pp0 += __shfl_xor(pp0, off, 64);
      pp1 += __shfl_xor(pp1, off, 64);
    }
    if (lane == 0) {
      float b = fcb[lr * 512 + srow];
      out[((size_t)0 * 18 + l) * 512 + srow] = fmaf(scale, pp0, b);
      out[((size_t)1 * 18 + l) * 512 + srow] = fmaf(scale, pp1, b);
    }
  }
}

extern "C" void kernel_launch(void* const* d_in, const int* in_sizes, int n_in,
                              void* d_out, int out_size, void* d_ws, size_t ws_size,
                              hipStream_t stream) {
  const int*   x   = (const int*)d_in[0];
  const float* w0  = (const float*)d_in[1];
  const float* cw  = (const float*)d_in[2];
  const float* cb  = (const float*)d_in[3];
  const float* pa  = (const float*)d_in[4];
  const float* fcw = (const float*)d_in[5];
  const float* fcb = (const float*)d_in[6];
  float* ws = (float*)d_ws;
  float* out = (float*)d_out;

  // tail: feat (43776 f32) + wf (32768 fp16 = 16384 f32 slots)
  const size_t tail = (size_t)2 * 18 * 1216 + WHALF / 2;
  #define NEED(n) (((size_t)(n) * PART + tail) * 4)

  int nblk;
  if      (ws_size >= NEED(1024)) nblk = 1024;
  else if (ws_size >= NEED(512))  nblk = 512;
  else                            nblk = 256;

  float* partial = ws;
  float* feat = ws + (size_t)nblk * PART;
  __fp16* wf = (__fp16*)(feat + (size_t)2 * 18 * 1216);
  const int per = nblk >> 5;    // blocks per kB1 y-slice (32 slices)

  hipLaunchKernelGGL(kW, dim3(WHALF / 256), dim3(256), 0, stream, cw, wf);

  if (nblk == 1024) {
    hipLaunchKernelGGL(kA<1>, dim3(1024), dim3(256), 0, stream,
                       x, w0, cw, cb, pa, wf, partial);
  } else if (nblk == 512) {
    hipLaunchKernelGGL(kA<2>, dim3(512), dim3(256), 0, stream,
                       x, w0, cw, cb, pa, wf, partial);
  } else {
    hipLaunchKernelGGL(kA<4>, dim3(256), dim3(256), 0, stream,
                       x, w0, cw, cb, pa, wf, partial);
  }

  hipLaunchKernelGGL(kB1, dim3(86, 32), dim3(256), 0, stream, partial, per);
  hipLaunchKernelGGL(kB2, dim3(86), dim3(256), 0, stream,
                     partial, per, cw, cb, pa, feat);
  hipLaunchKernelGGL(kC, dim3(32, 18), dim3(256), 0, stream, feat, fcw, fcb, out);
}